// Round 15
// baseline (56.475 us; speedup 1.0000x reference)
//
#include <hip/hip_runtime.h>

typedef float f32x4 __attribute__((ext_vector_type(4)));
typedef short bf16x8 __attribute__((ext_vector_type(8)));
typedef unsigned long long u64;

__device__ __forceinline__ short f2bf(float f) {
    union { float f; unsigned u; } c; c.f = f;
    unsigned r = (c.u + 0x7fffu + ((c.u >> 16) & 1u)) >> 16;
    return (short)r;
}
__device__ __forceinline__ unsigned pk2(float a, float b) {
    return (unsigned)(unsigned short)f2bf(a) | ((unsigned)(unsigned short)f2bf(b) << 16);
}

#define XT_S 296
#define AY_S 136
#define ZL_S 68

// ws layout (shorts): Dext frags | W1 frags | W2 frags | x_frag | y_frag | valp(f32)
#define DEXT_SHORTS (18*4*512)
#define W1_SHORTS   (99*512)
#define W2_SHORTS   (16*512)
#define WS2_SHORTS  (DEXT_SHORTS + W1_SHORTS + W2_SHORTS)   // 95744 shorts
#define RG_X 4608   // shorts per 16-row group in x_frag (9 kc * 512)
#define RG_Y 2048   // shorts per 16-row group in y_frag (4 kc * 512)

__device__ __forceinline__ int m8(int x, int y) {
    constexpr int M8[8][8] = {
        {0,1,2,3,3,2,1,0},{1,4,5,6,6,5,4,1},{2,5,7,8,8,7,5,2},{3,6,8,9,9,8,6,3},
        {3,6,8,9,9,8,6,3},{2,5,7,8,8,7,5,2},{1,4,5,6,6,5,4,1},{0,1,2,3,3,2,1,0}};
    return M8[x][y];
}

// ---- one-time: params/weights -> bf16 MFMA fragment layout (validated R8) ----
__global__ __launch_bounds__(256) void prep2(
    const float* __restrict__ myp,  const float* __restrict__ hisp,
    const float* __restrict__ w1a,  const float* __restrict__ w1v,
    const float* __restrict__ w2a,  short* __restrict__ ws)
{
    int i = blockIdx.x * 256 + threadIdx.x;
    if (i >= WS2_SHORTS) return;
    float v = 0.f;
    if (i < DEXT_SHORTS) {
        int e = i & 7, lane = (i >> 3) & 63, tc = i >> 9;
        int nt = tc >> 2, kc = tc & 3;
        int n = nt * 16 + (lane & 15);
        int k = kc * 32 + (lane >> 4) * 8 + e;
        int p = k >> 6, cell = k & 63, x = cell >> 3, y = cell & 7;
        const float* pr = p ? hisp : myp;
        if (n < 276) {
            bool match = false; int j = 0;
            if (n < 48)       { int p2 = n & 1, t = n >> 1; j = t >> 3; match = (p2 == p) && ((t & 7) == x); }
            else if (n < 96)  { int m = n - 48, p2 = m & 1, t = m >> 1; j = t >> 3; match = (p2 == p) && ((t & 7) == y); }
            else if (n < 186) { int m = n - 96, p2 = m & 1, t = m >> 1; j = t / 15;
                                match = (p2 == p) && ((t % 15) == ((y >= x) ? (y - x) : (x - y + 7))); }
            else              { int m = n - 186, p2 = m & 1, t = m >> 1; j = t / 15;
                                match = (p2 == p) && ((t % 15) == (x + y)); }
            if (match) v = pr[j * 10 + m8(x, y)];
        }
    } else if (i < DEXT_SHORTS + W1_SHORTS) {
        int ii = i - DEXT_SHORTS;
        int e = ii & 7, lane = (ii >> 3) & 63, tc = ii >> 9;
        int nt = tc / 9, kc = tc % 9;
        int n = nt * 16 + (lane & 15);
        int k = kc * 32 + (lane >> 4) * 8 + e;
        if (k < 276) {
            if (n < 100)                  v = w1a[n * 276 + k];
            else if (n >= 112 && n < 176) v = w1v[(n - 112) * 276 + k];
        }
    } else {
        int ii = i - DEXT_SHORTS - W1_SHORTS;
        int e = ii & 7, lane = (ii >> 3) & 63, tc = ii >> 9;
        int n = (tc >> 2) * 16 + (lane & 15);
        int k = (tc & 3) * 32 + (lane >> 4) * 8 + e;
        if (k < 100) v = w2a[n * 100 + k];
    }
    ws[i] = f2bf(v);
}

// ==== Kernel A: conv. 1 wave = 16 rows; swapped mfma(Dext, state); x -> frag layout.
// No LDS, no barriers. ====
__global__ __launch_bounds__(256) void conv_split(
    const float* __restrict__ state, const short* __restrict__ ws,
    short* __restrict__ xf, int ngrp)
{
    const int tid = threadIdx.x;
    const int wv = tid >> 6, l = tid & 63;
    const int lq = l >> 4, lr = l & 15;
    const int grp = blockIdx.x * 4 + wv;
    if (grp >= ngrp) return;
    bf16x8 sf[4];
    {
        const float* sp = state + (size_t)(grp * 16 + lr) * 128 + lq * 8;
        #pragma unroll
        for (int kc = 0; kc < 4; ++kc) {
            f32x4 lo = *(const f32x4*)(sp + kc * 32);
            f32x4 hi = *(const f32x4*)(sp + kc * 32 + 4);
            bf16x8 r;
            #pragma unroll
            for (int e = 0; e < 4; ++e) { r[e] = f2bf(lo[e]); r[4 + e] = f2bf(hi[e]); }
            sf[kc] = r;
        }
    }
    const int qbase = lq >> 1, e0 = (lq & 1) << 2;
    short* xg = xf + (size_t)grp * RG_X;
    #pragma unroll
    for (int nt = 0; nt < 18; ++nt) {
        f32x4 c = (f32x4){0.f, 0.f, 0.f, 0.f};
        #pragma unroll
        for (int kc = 0; kc < 4; ++kc) {
            bf16x8 d = *(const bf16x8*)(ws + ((nt * 4 + kc) * 64 + l) * 8);
            c = __builtin_amdgcn_mfma_f32_16x16x32_bf16(d, sf[kc], c, 0, 0, 0);
        }
        unsigned lo = pk2(fmaxf(c[0], 0.f), fmaxf(c[1], 0.f));
        unsigned hi = pk2(fmaxf(c[2], 0.f), fmaxf(c[3], 0.f));
        const int qp = ((nt & 1) << 1) | qbase;
        *(u64*)(xg + (nt >> 1) * 512 + (qp * 16 + lr) * 8 + e0) =
            (u64)lo | ((u64)hi << 32);
    }
}

// ==== Kernel B: GEMM1 (swapped, mfma(W1, x)); act -> y frag layout; val -> partials.
// Block = 6 waves (wave w: ntA=w, ntB=w+6); no LDS, no barriers. ====
__global__ __launch_bounds__(384) void gemm1_split(
    const short* __restrict__ ws, const short* __restrict__ xf,
    short* __restrict__ yf, float* __restrict__ valp,
    const float* __restrict__ b1a, const float* __restrict__ b1v,
    const float* __restrict__ w2v)
{
    const int tid = threadIdx.x, w = tid >> 6, l = tid & 63;
    const int lq = l >> 4, lr = l & 15;
    const int t = blockIdx.x;
    const bool haveB = (w < 5);
    const int ntA = w, ntB = w + 6;

    bf16x8 fA[9], fB[9];
    #pragma unroll
    for (int kc = 0; kc < 9; ++kc)
        fA[kc] = *(const bf16x8*)(ws + DEXT_SHORTS + ((ntA * 9 + kc) * 64 + l) * 8);
    if (haveB) {
        #pragma unroll
        for (int kc = 0; kc < 9; ++kc)
            fB[kc] = *(const bf16x8*)(ws + DEXT_SHORTS + ((ntB * 9 + kc) * 64 + l) * 8);
    }
    // per-lane bias/weight vectors (swapped layout: lane owns 4 consecutive cols)
    f32x4 bA = *(const f32x4*)(b1a + ntA * 16 + lq * 4);        // ntA<=5 -> cols<100
    f32x4 bB = (f32x4){0.f,0.f,0.f,0.f}, wB = (f32x4){0.f,0.f,0.f,0.f};
    if (w == 0) {
        if (lq == 0) bB = *(const f32x4*)(b1a + 96);            // cols 96..99
    } else if (haveB) {
        bB = *(const f32x4*)(b1v + (ntB - 7) * 16 + lq * 4);
        wB = *(const f32x4*)(w2v + (ntB - 7) * 16 + lq * 4);
    }
    const int qbase = lq >> 1, e0 = (lq & 1) << 2;

    #pragma unroll
    for (int mt = 0; mt < 4; ++mt) {
        const int grp = t * 4 + mt;
        const short* xg = xf + (size_t)grp * RG_X;
        bf16x8 a[9];
        #pragma unroll
        for (int kc = 0; kc < 9; ++kc)
            a[kc] = *(const bf16x8*)(xg + kc * 512 + l * 8);
        f32x4 zA = (f32x4){0.f,0.f,0.f,0.f}, zB = (f32x4){0.f,0.f,0.f,0.f};
        #pragma unroll
        for (int kc = 0; kc < 9; ++kc)
            zA = __builtin_amdgcn_mfma_f32_16x16x32_bf16(fA[kc], a[kc], zA, 0, 0, 0);
        if (haveB) {
            #pragma unroll
            for (int kc = 0; kc < 9; ++kc)
                zB = __builtin_amdgcn_mfma_f32_16x16x32_bf16(fB[kc], a[kc], zB, 0, 0, 0);
        }
        short* yg = yf + (size_t)grp * RG_Y;
        // act tile A: cols ntA*16 + lq*4 + r, row lr
        {
            unsigned lo = pk2(fmaxf(zA[0] + bA[0], 0.f), fmaxf(zA[1] + bA[1], 0.f));
            unsigned hi = pk2(fmaxf(zA[2] + bA[2], 0.f), fmaxf(zA[3] + bA[3], 0.f));
            const int qp = ((ntA & 1) << 1) | qbase;
            *(u64*)(yg + (ntA >> 1) * 512 + (qp * 16 + lr) * 8 + e0) =
                (u64)lo | ((u64)hi << 32);
        }
        if (w == 0) {
            // ntB=6: act cols 96..99 real (lq==0); cols 100..111 forced zero
            float v0 = (lq == 0) ? fmaxf(zB[0] + bB[0], 0.f) : 0.f;
            float v1 = (lq == 0) ? fmaxf(zB[1] + bB[1], 0.f) : 0.f;
            float v2 = (lq == 0) ? fmaxf(zB[2] + bB[2], 0.f) : 0.f;
            float v3 = (lq == 0) ? fmaxf(zB[3] + bB[3], 0.f) : 0.f;
            unsigned lo = pk2(v0, v1), hi = pk2(v2, v3);
            const int qp = qbase;                       // (6&1)=0
            *(u64*)(yg + 3 * 512 + (qp * 16 + lr) * 8 + e0) =
                (u64)lo | ((u64)hi << 32);
        } else if (haveB) {
            float s = fmaxf(zB[0] + bB[0], 0.f) * wB[0]
                    + fmaxf(zB[1] + bB[1], 0.f) * wB[1]
                    + fmaxf(zB[2] + bB[2], 0.f) * wB[2]
                    + fmaxf(zB[3] + bB[3], 0.f) * wB[3];
            s += __shfl_xor(s, 16);
            s += __shfl_xor(s, 32);
            if (lq == 0) valp[t * 256 + (w - 1) * 64 + mt * 16 + lr] = s;
            if (w == 1) {   // zero-fill y cols 112..127 (K-pad for GEMM2)
                const int qp = 2 | qbase;               // ntB=7: (7&1)<<1 = 2
                *(u64*)(yg + 3 * 512 + (qp * 16 + lr) * 8 + e0) = 0ULL;
            }
        }
    }
}

// ==== Kernel C: GEMM2 + in-register log-softmax + val tanh. 1 wave = 16 rows.
// No LDS, no barriers. ====
__global__ __launch_bounds__(256) void gemm2_split(
    const short* __restrict__ ws, const short* __restrict__ yf,
    const float* __restrict__ valp, const float* __restrict__ b2a,
    const float* __restrict__ b2v, float* __restrict__ out, int Btot)
{
    const int tid = threadIdx.x, wv = tid >> 6, l = tid & 63;
    const int lq = l >> 4, lr = l & 15;
    const int t = blockIdx.x;
    const int grp = t * 4 + wv, row0 = grp * 16;

    bf16x8 a2[4];
    const short* yg = yf + (size_t)grp * RG_Y;
    #pragma unroll
    for (int kc = 0; kc < 4; ++kc)
        a2[kc] = *(const bf16x8*)(yg + kc * 512 + l * 8);

    f32x4 z[4];
    float bias[4];
    #pragma unroll
    for (int nt = 0; nt < 4; ++nt) {
        z[nt] = (f32x4){0.f, 0.f, 0.f, 0.f};
        bias[nt] = b2a[nt * 16 + lr];
    }
    #pragma unroll
    for (int nt = 0; nt < 4; ++nt)
        #pragma unroll
        for (int kc = 0; kc < 4; ++kc) {
            bf16x8 wb = *(const bf16x8*)(ws + DEXT_SHORTS + W1_SHORTS + ((nt * 4 + kc) * 64 + l) * 8);
            z[nt] = __builtin_amdgcn_mfma_f32_16x16x32_bf16(a2[kc], wb, z[nt], 0, 0, 0);
        }
    #pragma unroll
    for (int nt = 0; nt < 4; ++nt)
        #pragma unroll
        for (int r = 0; r < 4; ++r) z[nt][r] += bias[nt];

    // softmax: row = row0 + lq*4 + r; cols over nt (regs) and lr (lanes, xor 1/2/4/8)
    #pragma unroll
    for (int r = 0; r < 4; ++r) {
        float m = fmaxf(fmaxf(z[0][r], z[1][r]), fmaxf(z[2][r], z[3][r]));
        m = fmaxf(m, __shfl_xor(m, 1));
        m = fmaxf(m, __shfl_xor(m, 2));
        m = fmaxf(m, __shfl_xor(m, 4));
        m = fmaxf(m, __shfl_xor(m, 8));
        float s = __expf(z[0][r] - m) + __expf(z[1][r] - m)
                + __expf(z[2][r] - m) + __expf(z[3][r] - m);
        s += __shfl_xor(s, 1);
        s += __shfl_xor(s, 2);
        s += __shfl_xor(s, 4);
        s += __shfl_xor(s, 8);
        const float lsm = m + __logf(s);
        float* o = out + (size_t)(row0 + lq * 4 + r) * 64 + lr;
        o[ 0] = z[0][r] - lsm;
        o[16] = z[1][r] - lsm;
        o[32] = z[2][r] - lsm;
        o[48] = z[3][r] - lsm;
    }
    // val head finish
    if (l < 16) {
        float v = valp[t * 256 +       wv * 16 + l]
                + valp[t * 256 +  64 + wv * 16 + l]
                + valp[t * 256 + 128 + wv * 16 + l]
                + valp[t * 256 + 192 + wv * 16 + l] + b2v[0];
        out[(size_t)Btot * 64 + row0 + l] = tanhf(v);
    }
}

// ==== fallback: R8's fused net_v3 (46 us, validated) ====
__global__ __launch_bounds__(384) void net_v3(
    const float* __restrict__ state,
    const float* __restrict__ b1a, const float* __restrict__ b2a,
    const float* __restrict__ b1v, const float* __restrict__ w2v,
    const float* __restrict__ b2v,
    const short* __restrict__ ws, float* __restrict__ out, int Btot)
{
    __shared__ __align__(16) unsigned char smem[56320];
    short* xt   = (short*)smem;
    float* zl   = (float*)smem;
    short* ay   = (short*)(smem + 37888);
    float* valp = (float*)(smem + 55296);
    const int tid  = threadIdx.x;
    const int w    = tid >> 6;
    const int l    = tid & 63;
    const int lrow = l & 15;
    const int lk   = l >> 4;
    const int bg0  = blockIdx.x * 64;
    {
        const float* sp = state + (size_t)bg0 * 128;
        #pragma unroll
        for (int it = 0; it < 6; ++it) {
            int t = tid + it * 384;
            if (t < 2048) {
                f32x4 v4 = *(const f32x4*)(sp + t * 4);
                int f = t * 4, row = f >> 7, col = f & 127;
                short* dst = ay + row * AY_S + col;
                dst[0] = f2bf(v4[0]); dst[1] = f2bf(v4[1]);
                dst[2] = f2bf(v4[2]); dst[3] = f2bf(v4[3]);
            }
        }
    }
    bf16x8 dx0[4], dx1[4], dx2[4];
    #pragma unroll
    for (int kc = 0; kc < 4; ++kc) {
        dx0[kc] = *(const bf16x8*)(ws + (((w     ) * 4 + kc) * 64 + l) * 8);
        dx1[kc] = *(const bf16x8*)(ws + (((w +  6) * 4 + kc) * 64 + l) * 8);
        dx2[kc] = *(const bf16x8*)(ws + (((w + 12) * 4 + kc) * 64 + l) * 8);
    }
    __syncthreads();
    {
        f32x4 c0[4], c1[4], c2[4];
        #pragma unroll
        for (int mt = 0; mt < 4; ++mt) {
            c0[mt] = (f32x4){0.f,0.f,0.f,0.f};
            c1[mt] = (f32x4){0.f,0.f,0.f,0.f};
            c2[mt] = (f32x4){0.f,0.f,0.f,0.f};
        }
        #pragma unroll
        for (int mt = 0; mt < 4; ++mt) {
            bf16x8 a[4];
            #pragma unroll
            for (int kc = 0; kc < 4; ++kc)
                a[kc] = *(const bf16x8*)(ay + (mt * 16 + lrow) * AY_S + kc * 32 + lk * 8);
            #pragma unroll
            for (int kc = 0; kc < 4; ++kc) {
                c0[mt] = __builtin_amdgcn_mfma_f32_16x16x32_bf16(a[kc], dx0[kc], c0[mt], 0, 0, 0);
                c1[mt] = __builtin_amdgcn_mfma_f32_16x16x32_bf16(a[kc], dx1[kc], c1[mt], 0, 0, 0);
                c2[mt] = __builtin_amdgcn_mfma_f32_16x16x32_bf16(a[kc], dx2[kc], c2[mt], 0, 0, 0);
            }
        }
        #pragma unroll
        for (int mt = 0; mt < 4; ++mt)
            #pragma unroll
            for (int r = 0; r < 4; ++r) {
                short* xr = xt + (mt * 16 + lk * 4 + r) * XT_S + lrow;
                xr[(w     ) * 16] = f2bf(fmaxf(c0[mt][r], 0.f));
                xr[(w +  6) * 16] = f2bf(fmaxf(c1[mt][r], 0.f));
                xr[(w + 12) * 16] = f2bf(fmaxf(c2[mt][r], 0.f));
            }
    }
    const bool haveB = (w < 5);
    bf16x8 bfA[9], bfB[9];
    #pragma unroll
    for (int kc = 0; kc < 9; ++kc)
        bfA[kc] = *(const bf16x8*)(ws + DEXT_SHORTS + ((w * 9 + kc) * 64 + l) * 8);
    if (haveB) {
        #pragma unroll
        for (int kc = 0; kc < 9; ++kc)
            bfB[kc] = *(const bf16x8*)(ws + DEXT_SHORTS + (((w + 6) * 9 + kc) * 64 + l) * 8);
    }
    float epbA, epbB = 0.f, epwB = 0.f;
    { const int colA = w * 16 + lrow; epbA = (colA < 100) ? b1a[colA] : 0.f; }
    if (haveB) {
        const int colB = (w + 6) * 16 + lrow;
        if (w == 0) epbB = (colB < 100) ? b1a[colB] : 0.f;
        else { epbB = b1v[colB - 112]; epwB = w2v[colB - 112]; }
    }
    __syncthreads();
    {
        f32x4 accA[4], accB[4];
        #pragma unroll
        for (int mt = 0; mt < 4; ++mt) {
            accA[mt] = (f32x4){0.f,0.f,0.f,0.f};
            accB[mt] = (f32x4){0.f,0.f,0.f,0.f};
        }
        #pragma unroll
        for (int mt = 0; mt < 4; ++mt) {
            bf16x8 a[9];
            #pragma unroll
            for (int kc = 0; kc < 9; ++kc)
                a[kc] = *(const bf16x8*)(xt + (mt * 16 + lrow) * XT_S + kc * 32 + lk * 8);
            #pragma unroll
            for (int kc = 0; kc < 9; ++kc)
                accA[mt] = __builtin_amdgcn_mfma_f32_16x16x32_bf16(a[kc], bfA[kc], accA[mt], 0, 0, 0);
            if (haveB) {
                #pragma unroll
                for (int kc = 0; kc < 9; ++kc)
                    accB[mt] = __builtin_amdgcn_mfma_f32_16x16x32_bf16(a[kc], bfB[kc], accB[mt], 0, 0, 0);
            }
        }
        #pragma unroll
        for (int mt = 0; mt < 4; ++mt)
            #pragma unroll
            for (int r = 0; r < 4; ++r) {
                float v = fmaxf(accA[mt][r] + epbA, 0.f);
                ay[(mt * 16 + lk * 4 + r) * AY_S + w * 16 + lrow] = f2bf(v);
            }
        if (haveB) {
            if (w == 0) {
                #pragma unroll
                for (int mt = 0; mt < 4; ++mt)
                    #pragma unroll
                    for (int r = 0; r < 4; ++r) {
                        const int row = mt * 16 + lk * 4 + r;
                        float v = fmaxf(accB[mt][r] + epbB, 0.f);
                        ay[row * AY_S +  96 + lrow] = f2bf(v);
                        ay[row * AY_S + 112 + lrow] = 0;
                    }
            } else {
                #pragma unroll
                for (int mt = 0; mt < 4; ++mt)
                    #pragma unroll
                    for (int r = 0; r < 4; ++r) {
                        float v = fmaxf(accB[mt][r] + epbB, 0.f) * epwB;
                        v += __shfl_xor(v, 1); v += __shfl_xor(v, 2);
                        v += __shfl_xor(v, 4); v += __shfl_xor(v, 8);
                        if (lrow == 0) valp[(w - 1) * 64 + mt * 16 + lk * 4 + r] = v;
                    }
            }
        }
    }
    bf16x8 b2f[4];
    float bias2 = 0.f;
    if (w < 4) {
        #pragma unroll
        for (int kc = 0; kc < 4; ++kc)
            b2f[kc] = *(const bf16x8*)(ws + DEXT_SHORTS + W1_SHORTS + ((w * 4 + kc) * 64 + l) * 8);
        bias2 = b2a[w * 16 + lrow];
    }
    __syncthreads();
    if (w < 4) {
        f32x4 acc2[4];
        #pragma unroll
        for (int mt = 0; mt < 4; ++mt) acc2[mt] = (f32x4){0.f,0.f,0.f,0.f};
        #pragma unroll
        for (int mt = 0; mt < 4; ++mt)
            #pragma unroll
            for (int kc = 0; kc < 4; ++kc) {
                bf16x8 a2 = *(const bf16x8*)(ay + (mt * 16 + lrow) * AY_S + kc * 32 + lk * 8);
                acc2[mt] = __builtin_amdgcn_mfma_f32_16x16x32_bf16(a2, b2f[kc], acc2[mt], 0, 0, 0);
            }
        #pragma unroll
        for (int mt = 0; mt < 4; ++mt)
            #pragma unroll
            for (int r = 0; r < 4; ++r)
                zl[(mt * 16 + lk * 4 + r) * ZL_S + w * 16 + lrow] = acc2[mt][r] + bias2;
    } else if (w == 5) {
        float v = valp[l] + valp[64 + l] + valp[128 + l] + valp[192 + l] + b2v[0];
        out[(size_t)Btot * 64 + bg0 + l] = tanhf(v);
    }
    __syncthreads();
    if (w < 4) {
        const int rl = l >> 2, q = l & 3;
        const int row = w * 16 + rl;
        const float* zr = zl + row * ZL_S;
        f32x4 v[4];
        float m = -1e30f;
        #pragma unroll
        for (int c = 0; c < 4; ++c) {
            v[c] = *(const f32x4*)(zr + c * 16 + q * 4);
            m = fmaxf(m, fmaxf(fmaxf(v[c][0], v[c][1]), fmaxf(v[c][2], v[c][3])));
        }
        m = fmaxf(m, __shfl_xor(m, 1));
        m = fmaxf(m, __shfl_xor(m, 2));
        float s = 0.f;
        #pragma unroll
        for (int c = 0; c < 4; ++c)
            #pragma unroll
            for (int e = 0; e < 4; ++e) s += __expf(v[c][e] - m);
        s += __shfl_xor(s, 1);
        s += __shfl_xor(s, 2);
        const float lsm = m + __logf(s);
        float* o = out + (size_t)(bg0 + row) * 64;
        #pragma unroll
        for (int c = 0; c < 4; ++c) {
            f32x4 ov;
            #pragma unroll
            for (int e = 0; e < 4; ++e) ov[e] = v[c][e] - lsm;
            *(f32x4*)(o + c * 16 + q * 4) = ov;
        }
    }
}

extern "C" void kernel_launch(void* const* d_in, const int* in_sizes, int n_in,
                              void* d_out, int out_size, void* d_ws, size_t ws_size,
                              hipStream_t stream) {
    const float* state = (const float*)d_in[0];
    const float* myp   = (const float*)d_in[1];
    const float* hisp  = (const float*)d_in[2];
    const float* w1a   = (const float*)d_in[3];
    const float* b1a   = (const float*)d_in[4];
    const float* w2a   = (const float*)d_in[5];
    const float* b2a   = (const float*)d_in[6];
    const float* w1v   = (const float*)d_in[7];
    const float* b1v   = (const float*)d_in[8];
    const float* w2v   = (const float*)d_in[9];
    const float* b2v   = (const float*)d_in[10];
    float* out = (float*)d_out;
    const int Btot  = in_sizes[0] / 128;        // (B,2,8,8)
    const int ntile = Btot / 64;
    const int ngrp  = Btot / 16;
    const size_t need_split =
        ((size_t)WS2_SHORTS + (size_t)ngrp * RG_X + (size_t)ngrp * RG_Y) * sizeof(short)
        + (size_t)ntile * 256 * sizeof(float);
    if (ws_size >= need_split) {
        short* ws     = (short*)d_ws;
        short* x_frag = ws + WS2_SHORTS;
        short* y_frag = x_frag + (size_t)ngrp * RG_X;
        float* valp   = (float*)(y_frag + (size_t)ngrp * RG_Y);
        prep2<<<dim3((WS2_SHORTS + 255) / 256), dim3(256), 0, stream>>>(myp, hisp, w1a, w1v, w2a, ws);
        conv_split <<<dim3(ntile), dim3(256), 0, stream>>>(state, ws, x_frag, ngrp);
        gemm1_split<<<dim3(ntile), dim3(384), 0, stream>>>(ws, x_frag, y_frag, valp, b1a, b1v, w2v);
        gemm2_split<<<dim3(ntile), dim3(256), 0, stream>>>(ws, y_frag, valp, b2a, b2v, out, Btot);
    } else {
        short* ws = (short*)d_ws;
        prep2<<<dim3((WS2_SHORTS + 255) / 256), dim3(256), 0, stream>>>(myp, hisp, w1a, w1v, w2a, ws);
        net_v3<<<dim3(ntile), dim3(384), 0, stream>>>(
            state, b1a, b2a, b1v, w2v, b2v, ws, out, Btot);
    }
}

// Round 16
// 47.126 us; speedup vs baseline: 1.1984x; 1.1984x over previous
//
#include <hip/hip_runtime.h>

typedef float f32x4 __attribute__((ext_vector_type(4)));
typedef short bf16x8 __attribute__((ext_vector_type(8)));

__device__ __forceinline__ short f2bf(float f) {
    union { float f; unsigned u; } c; c.f = f;
    unsigned r = (c.u + 0x7fffu + ((c.u >> 16) & 1u)) >> 16;
    return (short)r;
}

#define XT_S 296        // shorts, x-feature tile stride (288 used + pad)
#define AY_S 136        // shorts, state-stage / y tile stride (128 + pad)

// ws layout (shorts): Dext frags | W1 frags | W2 frags (validated R4/R8)
#define DEXT_SHORTS (18*4*512)
#define W1_SHORTS   (99*512)
#define W2_SHORTS   (16*512)
#define WS2_SHORTS  (DEXT_SHORTS + W1_SHORTS + W2_SHORTS)   // 95744 shorts = 191488 B

__device__ __forceinline__ int m8(int x, int y) {
    constexpr int M8[8][8] = {
        {0,1,2,3,3,2,1,0},{1,4,5,6,6,5,4,1},{2,5,7,8,8,7,5,2},{3,6,8,9,9,8,6,3},
        {3,6,8,9,9,8,6,3},{2,5,7,8,8,7,5,2},{1,4,5,6,6,5,4,1},{0,1,2,3,3,2,1,0}};
    return M8[x][y];
}

// ---- one-time: params/weights -> bf16 MFMA fragment layout in ws (validated R8) ----
__global__ __launch_bounds__(256) void prep2(
    const float* __restrict__ myp,  const float* __restrict__ hisp,
    const float* __restrict__ w1a,  const float* __restrict__ w1v,
    const float* __restrict__ w2a,  short* __restrict__ ws)
{
    int i = blockIdx.x * 256 + threadIdx.x;
    if (i >= WS2_SHORTS) return;
    float v = 0.f;
    if (i < DEXT_SHORTS) {
        int e = i & 7, lane = (i >> 3) & 63, tc = i >> 9;   // tc = nt*4+kc
        int nt = tc >> 2, kc = tc & 3;
        int n = nt * 16 + (lane & 15);
        int k = kc * 32 + (lane >> 4) * 8 + e;              // 0..127
        int p = k >> 6, cell = k & 63, x = cell >> 3, y = cell & 7;
        const float* pr = p ? hisp : myp;
        if (n < 276) {
            bool match = false; int j = 0;
            if (n < 48)       { int p2 = n & 1, t = n >> 1; j = t >> 3; match = (p2 == p) && ((t & 7) == x); }
            else if (n < 96)  { int m = n - 48, p2 = m & 1, t = m >> 1; j = t >> 3; match = (p2 == p) && ((t & 7) == y); }
            else if (n < 186) { int m = n - 96, p2 = m & 1, t = m >> 1; j = t / 15;
                                match = (p2 == p) && ((t % 15) == ((y >= x) ? (y - x) : (x - y + 7))); }
            else              { int m = n - 186, p2 = m & 1, t = m >> 1; j = t / 15;
                                match = (p2 == p) && ((t % 15) == (x + y)); }
            if (match) v = pr[j * 10 + m8(x, y)];
        }
    } else if (i < DEXT_SHORTS + W1_SHORTS) {
        int ii = i - DEXT_SHORTS;
        int e = ii & 7, lane = (ii >> 3) & 63, tc = ii >> 9; // tc = nt*9+kc
        int nt = tc / 9, kc = tc % 9;
        int n = nt * 16 + (lane & 15);
        int k = kc * 32 + (lane >> 4) * 8 + e;
        if (k < 276) {
            if (n < 100)                  v = w1a[n * 276 + k];
            else if (n >= 112 && n < 176) v = w1v[(n - 112) * 276 + k];
        }
    } else {
        int ii = i - DEXT_SHORTS - W1_SHORTS;
        int e = ii & 7, lane = (ii >> 3) & 63, tc = ii >> 9; // tc = nt*4+kc
        int n = (tc >> 2) * 16 + (lane & 15);
        int k = (tc & 3) * 32 + (lane >> 4) * 8 + e;
        if (k < 100) v = w2a[n * 100 + k];
    }
    ws[i] = f2bf(v);
}

// ---- v11: R8's net_v3 with P3+P4 merged into one phase (in-register GEMM2 +
// softmax per wave-owned rows, validated as gemm2_split in R15). 3 barriers. ----
__global__ __launch_bounds__(384) void net_v11(
    const float* __restrict__ state,
    const float* __restrict__ b1a, const float* __restrict__ b2a,
    const float* __restrict__ b1v, const float* __restrict__ w2v,
    const float* __restrict__ b2v,
    const short* __restrict__ ws, float* __restrict__ out, int Btot)
{
    __shared__ __align__(16) unsigned char smem[56320];
    short* xt   = (short*)smem;                 // [64][296] bf16 features (P1->P2)
    short* ay   = (short*)(smem + 37888);       // [64][136]: state stage (P0->P1), y (P2->P3)
    float* valp = (float*)(smem + 55296);       // [4][64] val partials

    const int tid  = threadIdx.x;
    const int w    = tid >> 6;      // wave 0..5
    const int l    = tid & 63;
    const int lrow = l & 15;
    const int lk   = l >> 4;
    const int bg0  = blockIdx.x * 64;

    // ---- P0: stage state (64 rows x 128 f32 = 32 KB) -> ay bf16, coalesced ----
    {
        const float* sp = state + (size_t)bg0 * 128;
        #pragma unroll
        for (int it = 0; it < 6; ++it) {
            int t = tid + it * 384;             // f32x4 index, < 2048
            if (t < 2048) {
                f32x4 v4 = *(const f32x4*)(sp + t * 4);
                int f = t * 4, row = f >> 7, col = f & 127;
                short* dst = ay + row * AY_S + col;
                dst[0] = f2bf(v4[0]); dst[1] = f2bf(v4[1]);
                dst[2] = f2bf(v4[2]); dst[3] = f2bf(v4[3]);
            }
        }
    }
    // conv B-frags, issued before barrier
    bf16x8 dx0[4], dx1[4], dx2[4];
    #pragma unroll
    for (int kc = 0; kc < 4; ++kc) {
        dx0[kc] = *(const bf16x8*)(ws + (((w     ) * 4 + kc) * 64 + l) * 8);
        dx1[kc] = *(const bf16x8*)(ws + (((w +  6) * 4 + kc) * 64 + l) * 8);
        dx2[kc] = *(const bf16x8*)(ws + (((w + 12) * 4 + kc) * 64 + l) * 8);
    }
    __syncthreads();

    // ---- P1: conv-GEMM  S[64,128] @ Dext[128,288] -> relu -> xt ----
    {
        f32x4 c0[4], c1[4], c2[4];
        #pragma unroll
        for (int mt = 0; mt < 4; ++mt) {
            c0[mt] = (f32x4){0.f,0.f,0.f,0.f};
            c1[mt] = (f32x4){0.f,0.f,0.f,0.f};
            c2[mt] = (f32x4){0.f,0.f,0.f,0.f};
        }
        #pragma unroll
        for (int mt = 0; mt < 4; ++mt) {
            bf16x8 a[4];
            #pragma unroll
            for (int kc = 0; kc < 4; ++kc)
                a[kc] = *(const bf16x8*)(ay + (mt * 16 + lrow) * AY_S + kc * 32 + lk * 8);
            #pragma unroll
            for (int kc = 0; kc < 4; ++kc) {
                c0[mt] = __builtin_amdgcn_mfma_f32_16x16x32_bf16(a[kc], dx0[kc], c0[mt], 0, 0, 0);
                c1[mt] = __builtin_amdgcn_mfma_f32_16x16x32_bf16(a[kc], dx1[kc], c1[mt], 0, 0, 0);
                c2[mt] = __builtin_amdgcn_mfma_f32_16x16x32_bf16(a[kc], dx2[kc], c2[mt], 0, 0, 0);
            }
        }
        #pragma unroll
        for (int mt = 0; mt < 4; ++mt)
            #pragma unroll
            for (int r = 0; r < 4; ++r) {
                short* xr = xt + (mt * 16 + lk * 4 + r) * XT_S + lrow;
                xr[(w     ) * 16] = f2bf(fmaxf(c0[mt][r], 0.f));
                xr[(w +  6) * 16] = f2bf(fmaxf(c1[mt][r], 0.f));
                xr[(w + 12) * 16] = f2bf(fmaxf(c2[mt][r], 0.f));
            }
    }
    // GEMM1 B-frags + epilogue constants (overlap with barrier)
    const bool haveB = (w < 5);
    bf16x8 bfA[9], bfB[9];
    #pragma unroll
    for (int kc = 0; kc < 9; ++kc)
        bfA[kc] = *(const bf16x8*)(ws + DEXT_SHORTS + ((w * 9 + kc) * 64 + l) * 8);
    if (haveB) {
        #pragma unroll
        for (int kc = 0; kc < 9; ++kc)
            bfB[kc] = *(const bf16x8*)(ws + DEXT_SHORTS + (((w + 6) * 9 + kc) * 64 + l) * 8);
    }
    float epbA, epbB = 0.f, epwB = 0.f;
    { const int colA = w * 16 + lrow; epbA = (colA < 100) ? b1a[colA] : 0.f; }
    if (haveB) {
        const int colB = (w + 6) * 16 + lrow;
        if (w == 0) epbB = (colB < 100) ? b1a[colB] : 0.f;     // nt=6: act tile
        else { epbB = b1v[colB - 112]; epwB = w2v[colB - 112]; } // nt=7..10: val tile
    }
    __syncthreads();

    // ---- P2: GEMM1  x[64,288] @ W1[288,176] ----
    {
        f32x4 accA[4], accB[4];
        #pragma unroll
        for (int mt = 0; mt < 4; ++mt) {
            accA[mt] = (f32x4){0.f,0.f,0.f,0.f};
            accB[mt] = (f32x4){0.f,0.f,0.f,0.f};
        }
        #pragma unroll
        for (int mt = 0; mt < 4; ++mt) {
            bf16x8 a[9];
            #pragma unroll
            for (int kc = 0; kc < 9; ++kc)
                a[kc] = *(const bf16x8*)(xt + (mt * 16 + lrow) * XT_S + kc * 32 + lk * 8);
            #pragma unroll
            for (int kc = 0; kc < 9; ++kc)
                accA[mt] = __builtin_amdgcn_mfma_f32_16x16x32_bf16(a[kc], bfA[kc], accA[mt], 0, 0, 0);
            if (haveB) {
                #pragma unroll
                for (int kc = 0; kc < 9; ++kc)
                    accB[mt] = __builtin_amdgcn_mfma_f32_16x16x32_bf16(a[kc], bfB[kc], accB[mt], 0, 0, 0);
            }
        }
        // epilogue tile A (always act: nt=w<=5): y cols w*16+lrow (0..95)
        #pragma unroll
        for (int mt = 0; mt < 4; ++mt)
            #pragma unroll
            for (int r = 0; r < 4; ++r) {
                float v = fmaxf(accA[mt][r] + epbA, 0.f);
                ay[(mt * 16 + lk * 4 + r) * AY_S + w * 16 + lrow] = f2bf(v);
            }
        if (haveB) {
            if (w == 0) {   // nt=6: act cols 96..111, plus zero K-pad cols 112..127
                #pragma unroll
                for (int mt = 0; mt < 4; ++mt)
                    #pragma unroll
                    for (int r = 0; r < 4; ++r) {
                        const int row = mt * 16 + lk * 4 + r;
                        float v = fmaxf(accB[mt][r] + epbB, 0.f);
                        ay[row * AY_S +  96 + lrow] = f2bf(v);
                        ay[row * AY_S + 112 + lrow] = 0;
                    }
            } else {        // nt=7..10: val tiles -> reduce over 16 cols -> valp
                #pragma unroll
                for (int mt = 0; mt < 4; ++mt)
                    #pragma unroll
                    for (int r = 0; r < 4; ++r) {
                        float v = fmaxf(accB[mt][r] + epbB, 0.f) * epwB;
                        v += __shfl_xor(v, 1); v += __shfl_xor(v, 2);
                        v += __shfl_xor(v, 4); v += __shfl_xor(v, 8);
                        if (lrow == 0) valp[(w - 1) * 64 + mt * 16 + lk * 4 + r] = v;
                    }
            }
        }
    }
    __syncthreads();

    // ---- P3' (merged): wave w<4 does GEMM2 for ITS rows w*16..w*16+15 across
    // ALL 4 N-tiles, then in-register log-softmax (validated math = R15's
    // gemm2_split). Wave 5: val tanh. No zl, no extra barrier, no P4. ----
    if (w < 4) {
        bf16x8 a2[4];
        #pragma unroll
        for (int kc = 0; kc < 4; ++kc)
            a2[kc] = *(const bf16x8*)(ay + (w * 16 + lrow) * AY_S + kc * 32 + lk * 8);
        f32x4 z[4];
        float bias[4];
        #pragma unroll
        for (int nt = 0; nt < 4; ++nt) {
            z[nt] = (f32x4){0.f, 0.f, 0.f, 0.f};
            bias[nt] = b2a[nt * 16 + lrow];
        }
        #pragma unroll
        for (int nt = 0; nt < 4; ++nt) {
            #pragma unroll
            for (int kc = 0; kc < 4; ++kc) {
                bf16x8 wb = *(const bf16x8*)(ws + DEXT_SHORTS + W1_SHORTS + ((nt * 4 + kc) * 64 + l) * 8);
                z[nt] = __builtin_amdgcn_mfma_f32_16x16x32_bf16(a2[kc], wb, z[nt], 0, 0, 0);
            }
            #pragma unroll
            for (int r = 0; r < 4; ++r) z[nt][r] += bias[nt];
        }
        // lane (lk,lrow) holds z[row = w*16 + lk*4 + r][col = nt*16 + lrow]
        #pragma unroll
        for (int r = 0; r < 4; ++r) {
            float m = fmaxf(fmaxf(z[0][r], z[1][r]), fmaxf(z[2][r], z[3][r]));
            m = fmaxf(m, __shfl_xor(m, 1));
            m = fmaxf(m, __shfl_xor(m, 2));
            m = fmaxf(m, __shfl_xor(m, 4));
            m = fmaxf(m, __shfl_xor(m, 8));
            float s = __expf(z[0][r] - m) + __expf(z[1][r] - m)
                    + __expf(z[2][r] - m) + __expf(z[3][r] - m);
            s += __shfl_xor(s, 1);
            s += __shfl_xor(s, 2);
            s += __shfl_xor(s, 4);
            s += __shfl_xor(s, 8);
            const float lsm = m + __logf(s);
            float* o = out + (size_t)(bg0 + w * 16 + lk * 4 + r) * 64 + lrow;
            o[ 0] = z[0][r] - lsm;
            o[16] = z[1][r] - lsm;
            o[32] = z[2][r] - lsm;
            o[48] = z[3][r] - lsm;
        }
    } else if (w == 5) {
        float v = valp[l] + valp[64 + l] + valp[128 + l] + valp[192 + l] + b2v[0];
        out[(size_t)Btot * 64 + bg0 + l] = tanhf(v);
    }
}

// ---- fallback (ws too small): weights straight from global (R8-shape v1) ----
__global__ __launch_bounds__(384) void net_v1(
    const float* __restrict__ state,
    const float* __restrict__ myp,  const float* __restrict__ hisp,
    const float* __restrict__ w1a,  const float* __restrict__ b1a,
    const float* __restrict__ w2a,  const float* __restrict__ b2a,
    const float* __restrict__ w1v,  const float* __restrict__ b1v,
    const float* __restrict__ w2v,  const float* __restrict__ b2v,
    float* __restrict__ out, int Btot)
{
    __shared__ __align__(16) unsigned char smem[56320];
    short* xt   = (short*)smem;
    float* zl   = (float*)smem;
    short* ay   = (short*)(smem + 37888);
    float* valp = (float*)(smem + 55296);
    const int tid = threadIdx.x, w = tid >> 6, l = tid & 63, lrow = l & 15, lk = l >> 4;
    const int bg0 = blockIdx.x * 64;
    const bool haveB = (w < 5);
    const int cp = (w >= 3) ? 1 : 0, cj = (w >= 3) ? (w - 3) : w;
    float prm[10];
    { const float* ps = (cp == 0 ? myp : hisp) + cj * 10;
      #pragma unroll
      for (int i = 0; i < 10; i++) prm[i] = ps[i]; }
    for (int i = tid; i < 9472; i += 384) ((unsigned*)xt)[i] = 0u;
    __syncthreads();
    {
        float racc[8], cacc[8], macc[15], aacc[15];
        #pragma unroll
        for (int i = 0; i < 8; i++) { racc[i] = 0.f; cacc[i] = 0.f; }
        #pragma unroll
        for (int i = 0; i < 15; i++) { macc[i] = 0.f; aacc[i] = 0.f; }
        const float* S = state + ((size_t)(bg0 + l) * 2 + cp) * 64;
        #pragma unroll
        for (int x = 0; x < 8; x++) {
            f32x4 lo = *(const f32x4*)(S + x * 8);
            f32x4 hi = *(const f32x4*)(S + x * 8 + 4);
            #pragma unroll
            for (int y = 0; y < 8; y++) {
                float s = (y < 4) ? lo[y] : hi[y - 4];
                float t = s * prm[m8(x, y)];
                racc[x] += t; cacc[y] += t;
                macc[(y >= x) ? (y - x) : (x - y + 7)] += t;
                aacc[x + y] += t;
            }
        }
        short* xr = xt + l * XT_S;
        #pragma unroll
        for (int i = 0; i < 8; i++)  xr[(cj * 8 + i) * 2 + cp]        = f2bf(fmaxf(racc[i], 0.f));
        #pragma unroll
        for (int i = 0; i < 8; i++)  xr[48 + (cj * 8 + i) * 2 + cp]   = f2bf(fmaxf(cacc[i], 0.f));
        #pragma unroll
        for (int k = 0; k < 15; k++) xr[96 + (cj * 15 + k) * 2 + cp]  = f2bf(fmaxf(macc[k], 0.f));
        #pragma unroll
        for (int k = 0; k < 15; k++) xr[186 + (cj * 15 + k) * 2 + cp] = f2bf(fmaxf(aacc[k], 0.f));
    }
    bf16x8 bfA[9], bfB[9];
    {
        const int nA = w * 16 + lrow;
        const float* srcA = (nA < 100) ? (w1a + (size_t)nA * 276) : w1a;
        #pragma unroll
        for (int kc = 0; kc < 9; kc++) {
            bf16x8 r;
            #pragma unroll
            for (int e = 0; e < 8; e++) {
                int k = kc * 32 + lk * 8 + e;
                bool ok = (nA < 100) && (k < 276);
                r[e] = f2bf(ok ? srcA[k] : 0.f);
            }
            bfA[kc] = r;
        }
        if (haveB) {
            const int nB = (w + 6) * 16 + lrow;
            const float* srcB; bool validB;
            if (nB < 100)       { srcB = w1a + (size_t)nB * 276;         validB = true; }
            else if (nB >= 112) { srcB = w1v + (size_t)(nB - 112) * 276; validB = true; }
            else                { srcB = w1a;                            validB = false; }
            #pragma unroll
            for (int kc = 0; kc < 9; kc++) {
                bf16x8 r;
                #pragma unroll
                for (int e = 0; e < 8; e++) {
                    int k = kc * 32 + lk * 8 + e;
                    bool ok = validB && (k < 276);
                    r[e] = f2bf(ok ? srcB[k] : 0.f);
                }
                bfB[kc] = r;
            }
        }
    }
    float epbA, epbB = 0.f, epwB = 0.f;
    { const int colA = w * 16 + lrow; epbA = (colA < 100) ? b1a[colA] : 0.f; }
    if (haveB) {
        const int colB = (w + 6) * 16 + lrow;
        if (w == 0) epbB = (colB < 100) ? b1a[colB] : 0.f;
        else { epbB = b1v[colB - 112]; epwB = w2v[colB - 112]; }
    }
    __syncthreads();
    {
        f32x4 accA[4], accB[4];
        #pragma unroll
        for (int mt = 0; mt < 4; ++mt) {
            accA[mt] = (f32x4){0.f,0.f,0.f,0.f};
            accB[mt] = (f32x4){0.f,0.f,0.f,0.f};
        }
        #pragma unroll
        for (int mt = 0; mt < 4; ++mt) {
            bf16x8 a[9];
            #pragma unroll
            for (int kc = 0; kc < 9; ++kc)
                a[kc] = *(const bf16x8*)(xt + (mt * 16 + lrow) * XT_S + kc * 32 + lk * 8);
            #pragma unroll
            for (int kc = 0; kc < 9; ++kc)
                accA[mt] = __builtin_amdgcn_mfma_f32_16x16x32_bf16(a[kc], bfA[kc], accA[mt], 0, 0, 0);
            if (haveB) {
                #pragma unroll
                for (int kc = 0; kc < 9; ++kc)
                    accB[mt] = __builtin_amdgcn_mfma_f32_16x16x32_bf16(a[kc], bfB[kc], accB[mt], 0, 0, 0);
            }
        }
        #pragma unroll
        for (int mt = 0; mt < 4; ++mt)
            #pragma unroll
            for (int r = 0; r < 4; ++r) {
                float v = fmaxf(accA[mt][r] + epbA, 0.f);
                ay[(mt * 16 + lk * 4 + r) * AY_S + w * 16 + lrow] = f2bf(v);
            }
        if (haveB) {
            if (w == 0) {
                #pragma unroll
                for (int mt = 0; mt < 4; ++mt)
                    #pragma unroll
                    for (int r = 0; r < 4; ++r) {
                        const int row = mt * 16 + lk * 4 + r;
                        float v = fmaxf(accB[mt][r] + epbB, 0.f);
                        ay[row * AY_S +  96 + lrow] = f2bf(v);
                        ay[row * AY_S + 112 + lrow] = 0;
                    }
            } else {
                #pragma unroll
                for (int mt = 0; mt < 4; ++mt)
                    #pragma unroll
                    for (int r = 0; r < 4; ++r) {
                        float v = fmaxf(accB[mt][r] + epbB, 0.f) * epwB;
                        v += __shfl_xor(v, 1); v += __shfl_xor(v, 2);
                        v += __shfl_xor(v, 4); v += __shfl_xor(v, 8);
                        if (lrow == 0) valp[(w - 1) * 64 + mt * 16 + lk * 4 + r] = v;
                    }
            }
        }
    }
    bf16x8 b2f[4];
    float bias2 = 0.f;
    if (w < 4) {
        const float* src2 = w2a + (size_t)(w * 16 + lrow) * 100;
        #pragma unroll
        for (int kc = 0; kc < 4; kc++) {
            bf16x8 r;
            #pragma unroll
            for (int e = 0; e < 8; e++) { int k = kc * 32 + lk * 8 + e; r[e] = f2bf((k < 100) ? src2[k] : 0.f); }
            b2f[kc] = r;
        }
        bias2 = b2a[w * 16 + lrow];
    }
    __syncthreads();
    if (w < 4) {
        f32x4 acc2[4];
        #pragma unroll
        for (int mt = 0; mt < 4; ++mt) acc2[mt] = (f32x4){0.f,0.f,0.f,0.f};
        #pragma unroll
        for (int mt = 0; mt < 4; ++mt)
            #pragma unroll
            for (int kc = 0; kc < 4; ++kc) {
                bf16x8 a2 = *(const bf16x8*)(ay + (mt * 16 + lrow) * AY_S + kc * 32 + lk * 8);
                acc2[mt] = __builtin_amdgcn_mfma_f32_16x16x32_bf16(a2, b2f[kc], acc2[mt], 0, 0, 0);
            }
        #pragma unroll
        for (int mt = 0; mt < 4; ++mt)
            #pragma unroll
            for (int r = 0; r < 4; ++r)
                zl[(mt * 16 + lk * 4 + r) * 68 + w * 16 + lrow] = acc2[mt][r] + bias2;
    } else if (w == 5) {
        float v = valp[l] + valp[64 + l] + valp[128 + l] + valp[192 + l] + b2v[0];
        out[(size_t)Btot * 64 + bg0 + l] = tanhf(v);
    }
    __syncthreads();
    if (w < 4) {
        const int rl = l >> 2, q = l & 3;
        const int row = w * 16 + rl;
        const float* zr = zl + row * 68;
        f32x4 v[4]; float m = -1e30f;
        #pragma unroll
        for (int c = 0; c < 4; ++c) {
            v[c] = *(const f32x4*)(zr + c * 16 + q * 4);
            m = fmaxf(m, fmaxf(fmaxf(v[c][0], v[c][1]), fmaxf(v[c][2], v[c][3])));
        }
        m = fmaxf(m, __shfl_xor(m, 1));
        m = fmaxf(m, __shfl_xor(m, 2));
        float s = 0.f;
        #pragma unroll
        for (int c = 0; c < 4; ++c)
            #pragma unroll
            for (int e = 0; e < 4; ++e) s += __expf(v[c][e] - m);
        s += __shfl_xor(s, 1);
        s += __shfl_xor(s, 2);
        const float lsm = m + __logf(s);
        float* o = out + (size_t)(bg0 + row) * 64;
        #pragma unroll
        for (int c = 0; c < 4; ++c) {
            f32x4 ov;
            #pragma unroll
            for (int e = 0; e < 4; ++e) ov[e] = v[c][e] - lsm;
            *(f32x4*)(o + c * 16 + q * 4) = ov;
        }
    }
}

extern "C" void kernel_launch(void* const* d_in, const int* in_sizes, int n_in,
                              void* d_out, int out_size, void* d_ws, size_t ws_size,
                              hipStream_t stream) {
    const float* state = (const float*)d_in[0];
    const float* myp   = (const float*)d_in[1];
    const float* hisp  = (const float*)d_in[2];
    const float* w1a   = (const float*)d_in[3];
    const float* b1a   = (const float*)d_in[4];
    const float* w2a   = (const float*)d_in[5];
    const float* b2a   = (const float*)d_in[6];
    const float* w1v   = (const float*)d_in[7];
    const float* b1v   = (const float*)d_in[8];
    const float* w2v   = (const float*)d_in[9];
    const float* b2v   = (const float*)d_in[10];
    float* out = (float*)d_out;
    const int Btot = in_sizes[0] / 128;          // (B,2,8,8)
    const int blocks = Btot / 64;
    if (ws_size >= (size_t)WS2_SHORTS * sizeof(short)) {
        short* ws = (short*)d_ws;
        prep2<<<dim3((WS2_SHORTS + 255) / 256), dim3(256), 0, stream>>>(myp, hisp, w1a, w1v, w2a, ws);
        net_v11<<<dim3(blocks), dim3(384), 0, stream>>>(
            state, b1a, b2a, b1v, w2v, b2v, ws, out, Btot);
    } else {
        net_v1<<<dim3(blocks), dim3(384), 0, stream>>>(
            state, myp, hisp, w1a, b1a, w2a, b2a, w1v, b1v, w2v, b2v, out, Btot);
    }
}